// Round 5
// baseline (97.565 us; speedup 1.0000x reference)
//
#include <hip/hip_runtime.h>
#include <hip/hip_bf16.h>
#include <stdint.h>

#define B_ 256
#define D_ 10
#define P_ 1152
#define I_ 16
#define J_ 8

#define PG 48        // p per k_uhat block
#define NPT 24       // p-groups (s_part slices)
#define SLOTS 9216   // u32 slots per (b,d) = P_*8
#define WSP 193      // padded LDS stride (PG*4 + 1 float4s)

__device__ inline uint32_t pack_bf16(float a, float b) {
    uint32_t ua = __float_as_uint(a);
    uint32_t ub = __float_as_uint(b);
    ua = (ua + 0x7fffu + ((ua >> 16) & 1u)) >> 16;
    ub = (ub + 0x7fffu + ((ub >> 16) & 1u)) >> 16;
    return ua | (ub << 16);
}

// uhat u32 layout per (b,d): slot = pq*32 + c*4 + p4   (p = pq*4+p4, c = i-pair)
// Block = (pg of 48 p, d, b-chunk of 64). Lane = (c, b-pair) loops p:
// each 64B W LDS fetch feeds TWO b (32 FMA) -> LDS traffic halved vs r4.
// s0 accumulates in registers (no barriers in loop); stores = full 128B lines.
// bid&7 pins each pg family to one XCD (x-cols + W slices stay L2-resident).
__global__ __launch_bounds__(256) void k_uhat(
    const float* __restrict__ x, const float* __restrict__ W,
    uint32_t* __restrict__ uhat, float* __restrict__ s_part)
{
    const int bid = blockIdx.x;
    const int g = bid & 7;
    const int fam = bid >> 3;            // 0..119
    const int pg = g + 8 * (fam % 3);    // 0..23
    const int rem = fam / 3;             // 0..39
    const int d = rem % D_;
    const int bc = rem / D_;             // 0..3

    const int p0 = pg * PG;
    const int tid = threadIdx.x;
    const int c = tid & 7;               // i-pair: i = 2c, 2c+1
    const int slot = tid >> 3;           // 0..31
    const int b0 = bc * 64 + slot * 2;   // lane owns b0, b0+1

    __shared__ float4 Wl[8 * WSP];       // 24,704 B

    // stage W[d, p0..p0+47]: global-contiguous reads, scattered one-time LDS writes
    const float4* wg = (const float4*)(W + (size_t)(d * P_ + p0) * 128);
    for (int k = tid; k < PG * 32; k += 256) {
        const int pl = k >> 5;
        const int cc = (k >> 2) & 7;
        const int q = k & 3;
        Wl[cc * WSP + pl * 4 + q] = wg[k];
    }
    __syncthreads();

    float s00 = 0.f, s01 = 0.f, s10 = 0.f, s11 = 0.f;
    const float4* xb0 = (const float4*)(x + ((size_t)b0 * P_ + p0) * J_);
    const float4* xb1 = xb0 + P_ * J_ / 4;
    uint4* ub0 = (uint4*)uhat + ((size_t)(b0 * D_ + d) * SLOTS >> 2) + c;
    uint4* ub1 = ub0 + (D_ * SLOTS >> 2);
    const int pqg0 = pg * 12;

    for (int pql = 0; pql < 12; ++pql) {
        uint32_t wr0[4], wr1[4];
        #pragma unroll
        for (int p4 = 0; p4 < 4; ++p4) {
            const int pl = pql * 4 + p4;
            const float4* wp = &Wl[c * WSP + pl * 4];
            const float4 wA = wp[0], wB = wp[1], wC = wp[2], wD = wp[3];

            const float4 xA0 = xb0[pl * 2], xB0 = xb0[pl * 2 + 1];
            float u0 = wA.x*xA0.x + wA.y*xA0.y + wA.z*xA0.z + wA.w*xA0.w
                     + wB.x*xB0.x + wB.y*xB0.y + wB.z*xB0.z + wB.w*xB0.w;
            float u1 = wC.x*xA0.x + wC.y*xA0.y + wC.z*xA0.z + wC.w*xA0.w
                     + wD.x*xB0.x + wD.y*xB0.y + wD.z*xB0.z + wD.w*xB0.w;
            s00 += u0; s01 += u1;
            wr0[p4] = pack_bf16(u0, u1);

            const float4 xA1 = xb1[pl * 2], xB1 = xb1[pl * 2 + 1];
            float v0 = wA.x*xA1.x + wA.y*xA1.y + wA.z*xA1.z + wA.w*xA1.w
                     + wB.x*xB1.x + wB.y*xB1.y + wB.z*xB1.z + wB.w*xB1.w;
            float v1 = wC.x*xA1.x + wC.y*xA1.y + wC.z*xA1.z + wC.w*xA1.w
                     + wD.x*xB1.x + wD.y*xB1.y + wD.z*xB1.z + wD.w*xB1.w;
            s10 += v0; s11 += v1;
            wr1[p4] = pack_bf16(v0, v1);
        }
        uint4 w4;
        w4.x = wr0[0]; w4.y = wr0[1]; w4.z = wr0[2]; w4.w = wr0[3];
        ub0[(size_t)(pqg0 + pql) * 8] = w4;
        w4.x = wr1[0]; w4.y = wr1[1]; w4.z = wr1[2]; w4.w = wr1[3];
        ub1[(size_t)(pqg0 + pql) * 8] = w4;
    }

    float2 o;
    o.x = s00; o.y = s01;
    *(float2*)&s_part[(((size_t)pg * B_ + b0) * D_ + d) * I_ + 2 * c] = o;
    o.x = s10; o.y = s11;
    *(float2*)&s_part[(((size_t)pg * B_ + b0 + 1) * D_ + d) * I_ + 2 * c] = o;
}

// Sum the 24 p-group partials -> s0 (x0.1), n2_0 = sum s0^2.
__global__ __launch_bounds__(256) void k_sred(const float* __restrict__ s_part,
                                              float* __restrict__ s, float* __restrict__ n2)
{
    const int gid = blockIdx.x * 256 + threadIdx.x;   // (b,d,i)
    float v = 0.f;
    #pragma unroll
    for (int pt = 0; pt < NPT; ++pt) v += s_part[(size_t)pt * (B_ * D_ * I_) + gid];
    v *= 0.1f;
    s[gid] = v;
    float v2 = v * v;
    #pragma unroll
    for (int st = 1; st < 64; st <<= 1) v2 += __shfl_xor(v2, st);
    __shared__ float r4[4];
    const int lane = threadIdx.x & 63, wave = threadIdx.x >> 6;
    if (lane == 0) r4[wave] = v2;
    __syncthreads();
    if (threadIdx.x == 0) atomicAdd(n2, r4[0] + r4[1] + r4[2] + r4[3]);
}

// Block per b. tls = g0*s0 (+ g1*s1 if rnd==2); logits = u_hat . tls;
// softmax over d; accumulate s_out, n2[rnd]. Wave reads 256B contiguous.
__global__ __launch_bounds__(1024) void k_route(
    const uint32_t* __restrict__ uhat,
    const float* __restrict__ s0, const float* __restrict__ s1,
    const float* __restrict__ n2v, int rnd,
    float* __restrict__ s_out)
{
    const int b = blockIdx.x;
    const int tid = threadIdx.x;

    __shared__ float tls[D_ * I_];
    __shared__ float sw[16][D_ * I_];
    __shared__ float n2l;

    if (tid < D_ * I_) {
        const float n20 = n2v[0];
        const float g0 = (n20 / (n20 + 1.f)) / (sqrtf(n20) + 1e-7f);
        float v = g0 * s0[(size_t)b * D_ * I_ + tid];
        if (rnd == 2) {
            const float n21 = n2v[1];
            const float g1 = (n21 / (n21 + 1.f)) / (sqrtf(n21) + 1e-7f);
            v += g1 * s1[(size_t)b * D_ * I_ + tid];
        }
        tls[tid] = v;
    }
    if (tid == 0) n2l = 0.f;
    __syncthreads();

    const int wv = tid >> 6;     // wave 0..15
    const int l = tid & 63;
    const int tb = l >> 3;       // team-in-wave 0..7
    const int tl = l & 7;        // i-pair
    const uint32_t* ubase = uhat + (size_t)b * D_ * SLOTS;

    float sacc[D_][2];
    #pragma unroll
    for (int d = 0; d < D_; ++d) { sacc[d][0] = 0.f; sacc[d][1] = 0.f; }

    for (int k = 0; k < 9; ++k) {
        const int pqb = k * 32 + wv * 2;
        const int slot = (pqb + (tb >> 2)) * 32 + tl * 4 + (tb & 3);
        const uint32_t* up = ubase + slot;
        float u[D_][2];
        float beta[D_];
        #pragma unroll
        for (int d = 0; d < D_; ++d) {
            const uint32_t w = up[(size_t)d * SLOTS];
            const float u0 = __uint_as_float(w << 16);
            const float u1 = __uint_as_float(w & 0xffff0000u);
            u[d][0] = u0; u[d][1] = u1;
            float bp = u0 * tls[d * I_ + 2 * tl] + u1 * tls[d * I_ + 2 * tl + 1];
            bp += __shfl_xor(bp, 1);
            bp += __shfl_xor(bp, 2);
            bp += __shfl_xor(bp, 4);
            beta[d] = bp;
        }
        float m = beta[0];
        #pragma unroll
        for (int d = 1; d < D_; ++d) m = fmaxf(m, beta[d]);
        float cc[D_]; float Z = 0.f;
        #pragma unroll
        for (int d = 0; d < D_; ++d) { cc[d] = __expf(beta[d] - m); Z += cc[d]; }
        const float rz = 1.f / Z;
        #pragma unroll
        for (int d = 0; d < D_; ++d) {
            const float cd = cc[d] * rz;
            sacc[d][0] += cd * u[d][0];
            sacc[d][1] += cd * u[d][1];
        }
    }

    #pragma unroll
    for (int st = 8; st < 64; st <<= 1) {
        #pragma unroll
        for (int d = 0; d < D_; ++d) {
            sacc[d][0] += __shfl_xor(sacc[d][0], st);
            sacc[d][1] += __shfl_xor(sacc[d][1], st);
        }
    }
    if (l < 8) {
        #pragma unroll
        for (int d = 0; d < D_; ++d) {
            sw[wv][d * I_ + 2 * tl]     = sacc[d][0];
            sw[wv][d * I_ + 2 * tl + 1] = sacc[d][1];
        }
    }
    __syncthreads();

    if (tid < D_ * I_) {
        float v = 0.f;
        #pragma unroll
        for (int w2 = 0; w2 < 16; ++w2) v += sw[w2][tid];
        s_out[(size_t)b * D_ * I_ + tid] = v;
        atomicAdd(&n2l, v * v);
    }
    __syncthreads();
    if (tid == 0) atomicAdd((float*)(n2v + rnd), n2l);
}

// Final in-place rescale: out *= g(n2_2)
__global__ void k_out(float* __restrict__ out, const float* __restrict__ n2p)
{
    const int i = blockIdx.x * 256 + threadIdx.x;
    const float n2 = *n2p;
    const float g = (n2 / (n2 + 1.f)) / (sqrtf(n2) + 1e-7f);
    out[i] *= g;
}

extern "C" void kernel_launch(void* const* d_in, const int* in_sizes, int n_in,
                              void* d_out, int out_size, void* d_ws, size_t ws_size,
                              hipStream_t stream)
{
    const float* x = (const float*)d_in[0];   // [256,1152,8]
    const float* W = (const float*)d_in[1];   // [10,1152,16,8]
    float* out = (float*)d_out;               // [256,10,16]

    char* ws = (char*)d_ws;
    uint32_t* uhat = (uint32_t*)ws;                              // bf16x2, 94,371,840 B
    const size_t uhat_bytes = (size_t)B_ * D_ * P_ * I_ * 2;
    float* s_part = (float*)(ws + uhat_bytes);                   // [24][B*D*I] = 3.93 MB
    float* s0 = s_part + (size_t)NPT * B_ * D_ * I_;             // [B*D*I]
    float* s1 = s0 + B_ * D_ * I_;                               // [B*D*I]
    float* n2 = s1 + B_ * D_ * I_;                               // [3]

    hipMemsetAsync(n2, 0, 3 * sizeof(float), stream);

    // r = 0: u_hat production + uniform-c (0.1) partial sums
    k_uhat<<<NPT * D_ * 4, 256, 0, stream>>>(x, W, uhat, s_part);
    k_sred<<<(B_ * D_ * I_) / 256, 256, 0, stream>>>(s_part, s0, n2 + 0);
    // r = 1: t = g0*s0
    k_route<<<B_, 1024, 0, stream>>>(uhat, s0, s1, n2, 1, s1);
    // r = 2: t = g0*s0 + g1*s1; raw s2 -> d_out
    k_route<<<B_, 1024, 0, stream>>>(uhat, s0, s1, n2, 2, out);
    // out = g2 * s2 (in place)
    k_out<<<(B_ * D_ * I_) / 256, 256, 0, stream>>>(out, n2 + 2);
}